// Round 1
// baseline (1247388.770 us; speedup 1.0000x reference)
//
#include <hip/hip_runtime.h>
#include <hip/hip_bf16.h>
#include <math.h>

#define T_STEPS 32768
#define HID 2048
#define EMB 2048

// ---------------------------------------------------------------------------
// Kernel A: XP = X[0:T-1] @ Wx + b, written to H rows 1..T-1 (row m -> m+1).
// fp32 vector GEMM (no fp32 MFMA on CDNA4), 64x64 tile, BK=16, 256 threads.
// ---------------------------------------------------------------------------
#define BM 64
#define BN 64
#define BK 16

__global__ __launch_bounds__(256) void xproj_gemm(const float* __restrict__ X,
                                                  const float* __restrict__ Wx,
                                                  const float* __restrict__ bias,
                                                  float* __restrict__ H)
{
    __shared__ __align__(16) float As[BK][BM];   // transposed A tile
    __shared__ __align__(16) float Bs[BK][BN];

    const int tid = threadIdx.x;
    const int m0 = blockIdx.y * BM;
    const int n0 = blockIdx.x * BN;

    const int tn = tid & 15;         // 0..15 (n micro-tile)
    const int tm = tid >> 4;         // 0..15 (m micro-tile)

    const int am = tid >> 2;         // 0..63  A-load row in tile
    const int ak = (tid & 3) << 2;   // 0,4,8,12
    const int bk = tid >> 4;         // 0..15  B-load row in k-tile
    const int bn = (tid & 15) << 2;  // 0..60

    const int arow = m0 + am;
    const bool aval = arow < (T_STEPS - 1);

    float acc[4][4];
#pragma unroll
    for (int i = 0; i < 4; ++i)
#pragma unroll
        for (int j = 0; j < 4; ++j) acc[i][j] = 0.f;

    for (int k0 = 0; k0 < EMB; k0 += BK) {
        float4 av = make_float4(0.f, 0.f, 0.f, 0.f);
        if (aval) av = *(const float4*)&X[(size_t)arow * EMB + k0 + ak];
        float4 bv = *(const float4*)&Wx[(size_t)(k0 + bk) * HID + n0 + bn];

        __syncthreads();
        As[ak + 0][am] = av.x;
        As[ak + 1][am] = av.y;
        As[ak + 2][am] = av.z;
        As[ak + 3][am] = av.w;
        *(float4*)&Bs[bk][bn] = bv;
        __syncthreads();

#pragma unroll
        for (int k = 0; k < BK; ++k) {
            float4 a4 = *(const float4*)&As[k][tm << 2];
            float4 b4 = *(const float4*)&Bs[k][tn << 2];
            acc[0][0] += a4.x * b4.x; acc[0][1] += a4.x * b4.y;
            acc[0][2] += a4.x * b4.z; acc[0][3] += a4.x * b4.w;
            acc[1][0] += a4.y * b4.x; acc[1][1] += a4.y * b4.y;
            acc[1][2] += a4.y * b4.z; acc[1][3] += a4.y * b4.w;
            acc[2][0] += a4.z * b4.x; acc[2][1] += a4.z * b4.y;
            acc[2][2] += a4.z * b4.z; acc[2][3] += a4.z * b4.w;
            acc[3][0] += a4.w * b4.x; acc[3][1] += a4.w * b4.y;
            acc[3][2] += a4.w * b4.z; acc[3][3] += a4.w * b4.w;
        }
    }

    float4 bb = *(const float4*)&bias[n0 + (tn << 2)];
#pragma unroll
    for (int i = 0; i < 4; ++i) {
        int m = m0 + (tm << 2) + i;
        if (m < T_STEPS - 1) {
            float4 o;
            o.x = acc[i][0] + bb.x;
            o.y = acc[i][1] + bb.y;
            o.z = acc[i][2] + bb.z;
            o.w = acc[i][3] + bb.w;
            *(float4*)&H[(size_t)(m + 1) * HID + n0 + (tn << 2)] = o;
        }
    }
}

// ---------------------------------------------------------------------------
// Kernel B: persistent cooperative scan. 256 blocks (1/CU) x 512 threads.
// Block owns 8 columns of Wh (in VGPRs: 32 regs/lane). Per step:
//   poll flags >= t  -> threadfence (L2 inv, per-XCD L2 non-coherent)
//   stage h_t row (8KB) into LDS -> per-wave column dot -> shfl reduce
//   tanh(xp + s) -> agent-scope store into H row t+1 -> barrier -> flag = t+1
// Skew between blocks is <= 1 step, so only one flag generation is needed.
// ---------------------------------------------------------------------------
#define NBLK 256
#define SCAN_TPB 512
#define CPB 8  // columns per block = HID / NBLK

__global__ __launch_bounds__(SCAN_TPB, 1) void rnn_scan(const float* __restrict__ Wh,
                                                        float* __restrict__ H,
                                                        unsigned int* __restrict__ flags)
{
    // 88 KB LDS: forbids 2 blocks/CU (160 KB pool) -> guaranteed 1 block/CU
    __shared__ __align__(16) float hlds[HID + 20480];

    const int tid = threadIdx.x;
    const int bid = blockIdx.x;
    const int wave = tid >> 6;   // 0..7 -> column within block
    const int lane = tid & 63;
    const int col = bid * CPB + wave;

    // Preload this lane's slice of Wh column `col`: rows 4*lane + 256*k (+0..3)
    float4 w[8];
#pragma unroll
    for (int k = 0; k < 8; ++k) {
        const int r = 4 * lane + 256 * k;
        const float* p = Wh + (size_t)r * HID + col;
        w[k].x = p[0];
        w[k].y = p[(size_t)HID];
        w[k].z = p[(size_t)(2 * HID)];
        w[k].w = p[(size_t)(3 * HID)];
    }

    for (int t = 0; t < T_STEPS - 1; ++t) {
        // Prefetch xp for this step (row t+1, own column). Safe: only this
        // lane ever writes H[t+1][col], and that happens later this step.
        float xpv = 0.f;
        if (lane == 0) xpv = H[(size_t)(t + 1) * HID + col];

        // Wait until every block has published row t (t=0: trivially ready).
        if (t > 0 && tid < NBLK) {
            while (__hip_atomic_load(&flags[tid], __ATOMIC_RELAXED,
                                     __HIP_MEMORY_SCOPE_AGENT) < (unsigned)t) {
            }
        }
        __syncthreads();
        __threadfence();  // acquire: invalidate L1/L2 so plain loads see row t

        // Stage h_t into LDS (512 threads x float4 = 8 KB, coalesced)
        {
            float4 hv = *(const float4*)&H[(size_t)t * HID + tid * 4];
            *(float4*)&hlds[tid * 4] = hv;
        }
        __syncthreads();

        // dot(h_t, Wh[:, col])
        float4 acc = make_float4(0.f, 0.f, 0.f, 0.f);
#pragma unroll
        for (int k = 0; k < 8; ++k) {
            float4 hh = *(const float4*)&hlds[4 * lane + 256 * k];
            acc.x += w[k].x * hh.x;
            acc.y += w[k].y * hh.y;
            acc.z += w[k].z * hh.z;
            acc.w += w[k].w * hh.w;
        }
        float s = (acc.x + acc.y) + (acc.z + acc.w);
        s += __shfl_xor(s, 1, 64);
        s += __shfl_xor(s, 2, 64);
        s += __shfl_xor(s, 4, 64);
        s += __shfl_xor(s, 8, 64);
        s += __shfl_xor(s, 16, 64);
        s += __shfl_xor(s, 32, 64);

        if (lane == 0) {
            float hv = tanhf(xpv + s);
            // bypass L2 to the coherence point so other XCDs can see it
            __hip_atomic_store(&H[(size_t)(t + 1) * HID + col], hv,
                               __ATOMIC_RELAXED, __HIP_MEMORY_SCOPE_AGENT);
        }
        __syncthreads();  // implies s_waitcnt vmcnt(0) per wave before barrier:
                          // all 8 column stores are globally visible now
        if (tid == 0) {
            __hip_atomic_store(&flags[bid], (unsigned)(t + 1),
                               __ATOMIC_RELEASE, __HIP_MEMORY_SCOPE_AGENT);
        }
    }
}

// ---------------------------------------------------------------------------
extern "C" void kernel_launch(void* const* d_in, const int* in_sizes, int n_in,
                              void* d_out, int out_size, void* d_ws, size_t ws_size,
                              hipStream_t stream)
{
    const float* X  = (const float*)d_in[0];
    const float* Wx = (const float*)d_in[1];
    const float* Wh = (const float*)d_in[2];
    const float* b  = (const float*)d_in[3];
    float* H = (float*)d_out;
    unsigned int* flags = (unsigned int*)d_ws;

    // H row 0 = h0 = zeros; flags = 0 (deterministic across graph replays)
    hipMemsetAsync(H, 0, HID * sizeof(float), stream);
    hipMemsetAsync(flags, 0, NBLK * sizeof(unsigned int), stream);

    dim3 ggrid(HID / BN, T_STEPS / BM);  // (32, 512)
    xproj_gemm<<<ggrid, 256, 0, stream>>>(X, Wx, b, H);

    const float* whp = Wh;
    float* hp = H;
    unsigned int* fp = flags;
    void* args[] = { (void*)&whp, (void*)&hp, (void*)&fp };
    hipLaunchCooperativeKernel((const void*)rnn_scan, dim3(NBLK), dim3(SCAN_TPB),
                               args, 0, stream);
}

// Round 2
// 169054.333 us; speedup vs baseline: 7.3786x; 7.3786x over previous
//
#include <hip/hip_runtime.h>
#include <hip/hip_bf16.h>
#include <math.h>

#define T_STEPS 32768
#define HID 2048
#define EMB 2048

// ---------------------------------------------------------------------------
// Kernel A: XP = X[0:T-1] @ Wx + b, written to H rows 1..T-1 (row m -> m+1).
// fp32 vector GEMM (no fp32 MFMA on CDNA4), 64x64 tile, BK=16, 256 threads.
// ---------------------------------------------------------------------------
#define BM 64
#define BN 64
#define BK 16

__global__ __launch_bounds__(256) void xproj_gemm(const float* __restrict__ X,
                                                  const float* __restrict__ Wx,
                                                  const float* __restrict__ bias,
                                                  float* __restrict__ H)
{
    __shared__ __align__(16) float As[BK][BM];   // transposed A tile
    __shared__ __align__(16) float Bs[BK][BN];

    const int tid = threadIdx.x;
    const int m0 = blockIdx.y * BM;
    const int n0 = blockIdx.x * BN;

    const int tn = tid & 15;         // 0..15 (n micro-tile)
    const int tm = tid >> 4;         // 0..15 (m micro-tile)

    const int am = tid >> 2;         // 0..63  A-load row in tile
    const int ak = (tid & 3) << 2;   // 0,4,8,12
    const int bk = tid >> 4;         // 0..15  B-load row in k-tile
    const int bn = (tid & 15) << 2;  // 0..60

    const int arow = m0 + am;
    const bool aval = arow < (T_STEPS - 1);

    float acc[4][4];
#pragma unroll
    for (int i = 0; i < 4; ++i)
#pragma unroll
        for (int j = 0; j < 4; ++j) acc[i][j] = 0.f;

    for (int k0 = 0; k0 < EMB; k0 += BK) {
        float4 av = make_float4(0.f, 0.f, 0.f, 0.f);
        if (aval) av = *(const float4*)&X[(size_t)arow * EMB + k0 + ak];
        float4 bv = *(const float4*)&Wx[(size_t)(k0 + bk) * HID + n0 + bn];

        __syncthreads();
        As[ak + 0][am] = av.x;
        As[ak + 1][am] = av.y;
        As[ak + 2][am] = av.z;
        As[ak + 3][am] = av.w;
        *(float4*)&Bs[bk][bn] = bv;
        __syncthreads();

#pragma unroll
        for (int k = 0; k < BK; ++k) {
            float4 a4 = *(const float4*)&As[k][tm << 2];
            float4 b4 = *(const float4*)&Bs[k][tn << 2];
            acc[0][0] += a4.x * b4.x; acc[0][1] += a4.x * b4.y;
            acc[0][2] += a4.x * b4.z; acc[0][3] += a4.x * b4.w;
            acc[1][0] += a4.y * b4.x; acc[1][1] += a4.y * b4.y;
            acc[1][2] += a4.y * b4.z; acc[1][3] += a4.y * b4.w;
            acc[2][0] += a4.z * b4.x; acc[2][1] += a4.z * b4.y;
            acc[2][2] += a4.z * b4.z; acc[2][3] += a4.z * b4.w;
            acc[3][0] += a4.w * b4.x; acc[3][1] += a4.w * b4.y;
            acc[3][2] += a4.w * b4.z; acc[3][3] += a4.w * b4.w;
        }
    }

    float4 bb = *(const float4*)&bias[n0 + (tn << 2)];
#pragma unroll
    for (int i = 0; i < 4; ++i) {
        int m = m0 + (tm << 2) + i;
        if (m < T_STEPS - 1) {
            float4 o;
            o.x = acc[i][0] + bb.x;
            o.y = acc[i][1] + bb.y;
            o.z = acc[i][2] + bb.z;
            o.w = acc[i][3] + bb.w;
            *(float4*)&H[(size_t)(m + 1) * HID + n0 + (tn << 2)] = o;
        }
    }
}

// ---------------------------------------------------------------------------
// Kernel B: persistent cooperative scan — FENCE-FREE handshake.
// All cross-block traffic uses relaxed agent-scope atomics (= global_load/
// store sc0 sc1: bypass L1+L2, hit the coherent memory-side Infinity Cache).
// No __threadfence / release fences -> no buffer_inv / buffer_wbl2 per step.
// Ordering: data stores -> s_waitcnt vmcnt(0) (ack from coherence point) ->
// s_barrier -> relaxed flag store. Consumers: relaxed flag poll -> relaxed
// data loads. Block skew is <=1 step, so one flag generation suffices.
// ---------------------------------------------------------------------------
#define NBLK 256
#define SCAN_TPB 512
#define CPB 8  // columns per block = HID / NBLK

__device__ __forceinline__ float2 agent_load_f2(const float* p)
{
    union { unsigned long long u; float2 f; } v;
    v.u = __hip_atomic_load((const unsigned long long*)p, __ATOMIC_RELAXED,
                            __HIP_MEMORY_SCOPE_AGENT);
    return v.f;
}

__global__ __launch_bounds__(SCAN_TPB, 1) void rnn_scan(const float* __restrict__ Wh,
                                                        float* __restrict__ H,
                                                        unsigned int* __restrict__ flags)
{
    // 88 KB LDS: forbids 2 blocks/CU (160 KB pool) -> guaranteed 1 block/CU
    __shared__ __align__(16) float hlds[HID + 20480];

    const int tid = threadIdx.x;
    const int bid = blockIdx.x;
    const int wave = tid >> 6;   // 0..7 -> column within block
    const int lane = tid & 63;
    const int col = bid * CPB + wave;

    // Preload this lane's slice of Wh column `col`: rows 4*lane + 256*k (+0..3)
    float4 w[8];
#pragma unroll
    for (int k = 0; k < 8; ++k) {
        const int r = 4 * lane + 256 * k;
        const float* p = Wh + (size_t)r * HID + col;
        w[k].x = p[0];
        w[k].y = p[(size_t)HID];
        w[k].z = p[(size_t)(2 * HID)];
        w[k].w = p[(size_t)(3 * HID)];
    }

    for (int t = 0; t < T_STEPS - 1; ++t) {
        // Prefetch xp for this step (row t+1, own column). Plain load is safe:
        // this location is only ever overwritten by THIS lane, later this step.
        float xpv = 0.f;
        if (lane == 0) xpv = H[(size_t)(t + 1) * HID + col];

        // Wait until every block has published row t (t=0: trivially ready).
        if (t > 0 && tid < NBLK) {
            while (__hip_atomic_load(&flags[tid], __ATOMIC_RELAXED,
                                     __HIP_MEMORY_SCOPE_AGENT) < (unsigned)t) {
            }
        }
        __syncthreads();

        // Stage h_t into LDS via L2-bypassing loads (2 x b64 per thread)
        {
            const float* src = &H[(size_t)t * HID + tid * 4];
            float2 a0 = agent_load_f2(src);
            float2 a1 = agent_load_f2(src + 2);
            *(float4*)&hlds[tid * 4] = make_float4(a0.x, a0.y, a1.x, a1.y);
        }
        __syncthreads();

        // dot(h_t, Wh[:, col])
        float4 acc = make_float4(0.f, 0.f, 0.f, 0.f);
#pragma unroll
        for (int k = 0; k < 8; ++k) {
            float4 hh = *(const float4*)&hlds[4 * lane + 256 * k];
            acc.x += w[k].x * hh.x;
            acc.y += w[k].y * hh.y;
            acc.z += w[k].z * hh.z;
            acc.w += w[k].w * hh.w;
        }
        float s = (acc.x + acc.y) + (acc.z + acc.w);
        s += __shfl_xor(s, 1, 64);
        s += __shfl_xor(s, 2, 64);
        s += __shfl_xor(s, 4, 64);
        s += __shfl_xor(s, 8, 64);
        s += __shfl_xor(s, 16, 64);
        s += __shfl_xor(s, 32, 64);

        if (lane == 0) {
            float hv = tanhf(xpv + s);
            // write-through to the coherence point (bypass L1/L2)
            __hip_atomic_store(&H[(size_t)(t + 1) * HID + col], hv,
                               __ATOMIC_RELAXED, __HIP_MEMORY_SCOPE_AGENT);
        }
        // Wave-wide: ensure this wave's store is ACK'd at the coherence point
        asm volatile("s_waitcnt vmcnt(0)" ::: "memory");
        __syncthreads();  // all 8 column stores globally visible now
        if (tid == 0) {
            __hip_atomic_store(&flags[bid], (unsigned)(t + 1),
                               __ATOMIC_RELAXED, __HIP_MEMORY_SCOPE_AGENT);
        }
    }
}

// ---------------------------------------------------------------------------
extern "C" void kernel_launch(void* const* d_in, const int* in_sizes, int n_in,
                              void* d_out, int out_size, void* d_ws, size_t ws_size,
                              hipStream_t stream)
{
    const float* X  = (const float*)d_in[0];
    const float* Wx = (const float*)d_in[1];
    const float* Wh = (const float*)d_in[2];
    const float* b  = (const float*)d_in[3];
    float* H = (float*)d_out;
    unsigned int* flags = (unsigned int*)d_ws;

    // H row 0 = h0 = zeros; flags = 0 (deterministic across graph replays)
    hipMemsetAsync(H, 0, HID * sizeof(float), stream);
    hipMemsetAsync(flags, 0, NBLK * sizeof(unsigned int), stream);

    dim3 ggrid(HID / BN, T_STEPS / BM);  // (32, 512)
    xproj_gemm<<<ggrid, 256, 0, stream>>>(X, Wx, b, H);

    const float* whp = Wh;
    float* hp = H;
    unsigned int* fp = flags;
    void* args[] = { (void*)&whp, (void*)&hp, (void*)&fp };
    hipLaunchCooperativeKernel((const void*)rnn_scan, dim3(NBLK), dim3(SCAN_TPB),
                               args, 0, stream);
}

// Round 3
// 156251.733 us; speedup vs baseline: 7.9832x; 1.0819x over previous
//
#include <hip/hip_runtime.h>
#include <hip/hip_bf16.h>
#include <math.h>

#define T_STEPS 32768
#define HID 2048
#define EMB 2048

// ---------------------------------------------------------------------------
// Kernel A: XP = X[0:T-1] @ Wx + b, written to H rows 1..T-1 (row m -> m+1).
// fp32 vector GEMM (no fp32 MFMA on CDNA4), 64x64 tile, BK=16, 256 threads.
// ---------------------------------------------------------------------------
#define BM 64
#define BN 64
#define BK 16

__global__ __launch_bounds__(256) void xproj_gemm(const float* __restrict__ X,
                                                  const float* __restrict__ Wx,
                                                  const float* __restrict__ bias,
                                                  float* __restrict__ H)
{
    __shared__ __align__(16) float As[BK][BM];   // transposed A tile
    __shared__ __align__(16) float Bs[BK][BN];

    const int tid = threadIdx.x;
    const int m0 = blockIdx.y * BM;
    const int n0 = blockIdx.x * BN;

    const int tn = tid & 15;         // 0..15 (n micro-tile)
    const int tm = tid >> 4;         // 0..15 (m micro-tile)

    const int am = tid >> 2;         // 0..63  A-load row in tile
    const int ak = (tid & 3) << 2;   // 0,4,8,12
    const int bk = tid >> 4;         // 0..15  B-load row in k-tile
    const int bn = (tid & 15) << 2;  // 0..60

    const int arow = m0 + am;
    const bool aval = arow < (T_STEPS - 1);

    float acc[4][4];
#pragma unroll
    for (int i = 0; i < 4; ++i)
#pragma unroll
        for (int j = 0; j < 4; ++j) acc[i][j] = 0.f;

    for (int k0 = 0; k0 < EMB; k0 += BK) {
        float4 av = make_float4(0.f, 0.f, 0.f, 0.f);
        if (aval) av = *(const float4*)&X[(size_t)arow * EMB + k0 + ak];
        float4 bv = *(const float4*)&Wx[(size_t)(k0 + bk) * HID + n0 + bn];

        __syncthreads();
        As[ak + 0][am] = av.x;
        As[ak + 1][am] = av.y;
        As[ak + 2][am] = av.z;
        As[ak + 3][am] = av.w;
        *(float4*)&Bs[bk][bn] = bv;
        __syncthreads();

#pragma unroll
        for (int k = 0; k < BK; ++k) {
            float4 a4 = *(const float4*)&As[k][tm << 2];
            float4 b4 = *(const float4*)&Bs[k][tn << 2];
            acc[0][0] += a4.x * b4.x; acc[0][1] += a4.x * b4.y;
            acc[0][2] += a4.x * b4.z; acc[0][3] += a4.x * b4.w;
            acc[1][0] += a4.y * b4.x; acc[1][1] += a4.y * b4.y;
            acc[1][2] += a4.y * b4.z; acc[1][3] += a4.y * b4.w;
            acc[2][0] += a4.z * b4.x; acc[2][1] += a4.z * b4.y;
            acc[2][2] += a4.z * b4.z; acc[2][3] += a4.z * b4.w;
            acc[3][0] += a4.w * b4.x; acc[3][1] += a4.w * b4.y;
            acc[3][2] += a4.w * b4.z; acc[3][3] += a4.w * b4.w;
        }
    }

    float4 bb = *(const float4*)&bias[n0 + (tn << 2)];
#pragma unroll
    for (int i = 0; i < 4; ++i) {
        int m = m0 + (tm << 2) + i;
        if (m < T_STEPS - 1) {
            float4 o;
            o.x = acc[i][0] + bb.x;
            o.y = acc[i][1] + bb.y;
            o.z = acc[i][2] + bb.z;
            o.w = acc[i][3] + bb.w;
            *(float4*)&H[(size_t)(m + 1) * HID + n0 + (tn << 2)] = o;
        }
    }
}

// ---------------------------------------------------------------------------
// Kernel B: persistent cooperative scan — SELF-ANNOUNCING DATA handshake.
// Each h element is published as an 8-byte {float val, uint step} entry via
// one relaxed agent-scope b64 atomic (L1/L2-bypass, coherent at the
// memory-side Infinity Cache). Consumers poll the entries themselves: when
// entry.step == t the value is already loaded — no flags, no vmcnt ack, no
// separate data load. hcomm and the LDS staging buffer are parity
// double-buffered; ONE __syncthreads per step (doubles as the skew
// certificate: passing the barrier proves this block finished polling h_t,
// which is what makes the t+2 overwrite of the same parity slot safe).
// ---------------------------------------------------------------------------
#define NBLK 256
#define SCAN_TPB 512
#define CPB 8  // columns per block = HID / NBLK

union EntryU {
    unsigned long long u;
    struct { float v; unsigned s; } e;
};

__device__ __forceinline__ unsigned long long agent_load_u64(const unsigned long long* p)
{
    return __hip_atomic_load(p, __ATOMIC_RELAXED, __HIP_MEMORY_SCOPE_AGENT);
}

__global__ __launch_bounds__(SCAN_TPB, 1) void rnn_scan(const float* __restrict__ Wh,
                                                        float* __restrict__ H,
                                                        unsigned long long* __restrict__ hcomm)
{
    // big LDS pad: forbids 2 blocks/CU (160 KB pool) -> guaranteed 1 block/CU,
    // so the 256 cooperative blocks map 1:1 onto the 256 CUs.
    __shared__ __align__(16) float hlds[2][HID];
    __shared__ __align__(16) float pad[18432];
    (void)pad;

    const int tid = threadIdx.x;
    const int bid = blockIdx.x;
    const int wave = tid >> 6;   // 0..7 -> column within block
    const int lane = tid & 63;
    const int col = bid * CPB + wave;

    // Preload this lane's slice of Wh column `col`: rows 4*lane + 256*k (+0..3)
    float4 w[8];
#pragma unroll
    for (int k = 0; k < 8; ++k) {
        const int r = 4 * lane + 256 * k;
        const float* p = Wh + (size_t)r * HID + col;
        w[k].x = p[0];
        w[k].y = p[(size_t)HID];
        w[k].z = p[(size_t)(2 * HID)];
        w[k].w = p[(size_t)(3 * HID)];
    }

    const int e0 = tid * 4;  // this thread's 4 owned entries

    for (int t = 0; t < T_STEPS - 1; ++t) {
        // Prefetch xp for this step (row t+1, own column). Plain load is safe:
        // only THIS lane overwrites that location, later this step. Latency
        // overlaps the poll below.
        float xpv = 0.f;
        if (lane == 0) xpv = H[(size_t)(t + 1) * HID + col];

        // Poll own 4 entries of h_t (parity buffer t&1). The poll IS the load.
        const unsigned long long* buf = hcomm + (size_t)(t & 1) * HID;
        const unsigned ts = (unsigned)t;
        float4 hv;
        for (;;) {
            EntryU a, b, c, d;
            a.u = agent_load_u64(buf + e0 + 0);
            b.u = agent_load_u64(buf + e0 + 1);
            c.u = agent_load_u64(buf + e0 + 2);
            d.u = agent_load_u64(buf + e0 + 3);
            if (a.e.s == ts && b.e.s == ts && c.e.s == ts && d.e.s == ts) {
                hv = make_float4(a.e.v, b.e.v, c.e.v, d.e.v);
                break;
            }
        }
        *(float4*)&hlds[t & 1][e0] = hv;
        __syncthreads();  // full h_t row staged; also certifies poll completion

        // dot(h_t, Wh[:, col])
        float4 acc = make_float4(0.f, 0.f, 0.f, 0.f);
#pragma unroll
        for (int k = 0; k < 8; ++k) {
            float4 hh = *(const float4*)&hlds[t & 1][4 * lane + 256 * k];
            acc.x += w[k].x * hh.x;
            acc.y += w[k].y * hh.y;
            acc.z += w[k].z * hh.z;
            acc.w += w[k].w * hh.w;
        }
        float s = (acc.x + acc.y) + (acc.z + acc.w);
        s += __shfl_xor(s, 1, 64);
        s += __shfl_xor(s, 2, 64);
        s += __shfl_xor(s, 4, 64);
        s += __shfl_xor(s, 8, 64);
        s += __shfl_xor(s, 16, 64);
        s += __shfl_xor(s, 32, 64);

        if (lane == 0) {
            float hvn = tanhf(xpv + s);
            // publish FIRST (critical path): {val, t+1} into parity slot (t+1)&1
            EntryU eu;
            eu.e.v = hvn;
            eu.e.s = (unsigned)(t + 1);
            __hip_atomic_store(&hcomm[(size_t)((t + 1) & 1) * HID + col], eu.u,
                               __ATOMIC_RELAXED, __HIP_MEMORY_SCOPE_AGENT);
            // output write (nobody else ever reads this during the scan)
            H[(size_t)(t + 1) * HID + col] = hvn;
        }
        // no trailing barrier: hlds is parity double-buffered, and intra-block
        // skew >1 step is impossible (a wave can't pass the t+1 poll until
        // every block — including this one — has published h_{t+1}).
    }
}

// ---------------------------------------------------------------------------
extern "C" void kernel_launch(void* const* d_in, const int* in_sizes, int n_in,
                              void* d_out, int out_size, void* d_ws, size_t ws_size,
                              hipStream_t stream)
{
    const float* X  = (const float*)d_in[0];
    const float* Wx = (const float*)d_in[1];
    const float* Wh = (const float*)d_in[2];
    const float* b  = (const float*)d_in[3];
    float* H = (float*)d_out;
    unsigned long long* hcomm = (unsigned long long*)d_ws;

    // H row 0 = h0 = zeros. hcomm = {0.0f, step=0} == h_0 entries (memset 0
    // gives exactly that), re-done every call for graph-replay determinism.
    hipMemsetAsync(H, 0, HID * sizeof(float), stream);
    hipMemsetAsync(hcomm, 0, 2 * HID * sizeof(unsigned long long), stream);

    dim3 ggrid(HID / BN, T_STEPS / BM);  // (32, 512)
    xproj_gemm<<<ggrid, 256, 0, stream>>>(X, Wx, b, H);

    const float* whp = Wh;
    float* hp = H;
    unsigned long long* cp = hcomm;
    void* args[] = { (void*)&whp, (void*)&hp, (void*)&cp };
    hipLaunchCooperativeKernel((const void*)rnn_scan, dim3(NBLK), dim3(SCAN_TPB),
                               args, 0, stream);
}

// Round 4
// 139792.310 us; speedup vs baseline: 8.9232x; 1.1177x over previous
//
#include <hip/hip_runtime.h>
#include <hip/hip_bf16.h>
#include <math.h>

#define T_STEPS 32768
#define HID 2048
#define EMB 2048

// ---------------------------------------------------------------------------
// Kernel A: XP = X[0:T-1] @ Wx + b, written to H rows 1..T-1 (row m -> m+1).
// fp32 vector GEMM (no fp32 MFMA on CDNA4), 64x64 tile, BK=16, 256 threads.
// ---------------------------------------------------------------------------
#define BM 64
#define BN 64
#define BK 16

__global__ __launch_bounds__(256) void xproj_gemm(const float* __restrict__ X,
                                                  const float* __restrict__ Wx,
                                                  const float* __restrict__ bias,
                                                  float* __restrict__ H)
{
    __shared__ __align__(16) float As[BK][BM];   // transposed A tile
    __shared__ __align__(16) float Bs[BK][BN];

    const int tid = threadIdx.x;
    const int m0 = blockIdx.y * BM;
    const int n0 = blockIdx.x * BN;

    const int tn = tid & 15;         // 0..15 (n micro-tile)
    const int tm = tid >> 4;         // 0..15 (m micro-tile)

    const int am = tid >> 2;         // 0..63  A-load row in tile
    const int ak = (tid & 3) << 2;   // 0,4,8,12
    const int bk = tid >> 4;         // 0..15  B-load row in k-tile
    const int bn = (tid & 15) << 2;  // 0..60

    const int arow = m0 + am;
    const bool aval = arow < (T_STEPS - 1);

    float acc[4][4];
#pragma unroll
    for (int i = 0; i < 4; ++i)
#pragma unroll
        for (int j = 0; j < 4; ++j) acc[i][j] = 0.f;

    for (int k0 = 0; k0 < EMB; k0 += BK) {
        float4 av = make_float4(0.f, 0.f, 0.f, 0.f);
        if (aval) av = *(const float4*)&X[(size_t)arow * EMB + k0 + ak];
        float4 bv = *(const float4*)&Wx[(size_t)(k0 + bk) * HID + n0 + bn];

        __syncthreads();
        As[ak + 0][am] = av.x;
        As[ak + 1][am] = av.y;
        As[ak + 2][am] = av.z;
        As[ak + 3][am] = av.w;
        *(float4*)&Bs[bk][bn] = bv;
        __syncthreads();

#pragma unroll
        for (int k = 0; k < BK; ++k) {
            float4 a4 = *(const float4*)&As[k][tm << 2];
            float4 b4 = *(const float4*)&Bs[k][tn << 2];
            acc[0][0] += a4.x * b4.x; acc[0][1] += a4.x * b4.y;
            acc[0][2] += a4.x * b4.z; acc[0][3] += a4.x * b4.w;
            acc[1][0] += a4.y * b4.x; acc[1][1] += a4.y * b4.y;
            acc[1][2] += a4.y * b4.z; acc[1][3] += a4.y * b4.w;
            acc[2][0] += a4.z * b4.x; acc[2][1] += a4.z * b4.y;
            acc[2][2] += a4.z * b4.z; acc[2][3] += a4.z * b4.w;
            acc[3][0] += a4.w * b4.x; acc[3][1] += a4.w * b4.y;
            acc[3][2] += a4.w * b4.z; acc[3][3] += a4.w * b4.w;
        }
    }

    float4 bb = *(const float4*)&bias[n0 + (tn << 2)];
#pragma unroll
    for (int i = 0; i < 4; ++i) {
        int m = m0 + (tm << 2) + i;
        if (m < T_STEPS - 1) {
            float4 o;
            o.x = acc[i][0] + bb.x;
            o.y = acc[i][1] + bb.y;
            o.z = acc[i][2] + bb.z;
            o.w = acc[i][3] + bb.w;
            *(float4*)&H[(size_t)(m + 1) * HID + n0 + (tn << 2)] = o;
        }
    }
}

// ---------------------------------------------------------------------------
// Kernel B: persistent cooperative scan — 64 CUs, low-congestion handshake.
// R2 lesson (counters): the limiter was poll-request QUEUEING at the TCC/IF$
// (65K uncached 8B lookups per XCD per poll round), not round-trip count.
// Now: 64 blocks x 1024 threads, block owns 32 contiguous columns (2/wave,
// 64 fp32 weights/lane). Each thread polls its 2 {val,step} entries with ONE
// 16B uncached load; producers publish 2 entries with ONE 16B store.
// Poll traffic: 8K req/XCD/round (8x less than R2). Self-announcing data,
// parity double-buffer, one barrier/step, in-place xp prefetch — unchanged.
// ---------------------------------------------------------------------------
#define NBLK 64
#define SCAN_TPB 1024
#define CPB 32  // cols per block
#define CPW 2   // cols per wave

typedef int v4i __attribute__((ext_vector_type(4)));

__device__ __forceinline__ v4i uncached_load16(const void* p)
{
    v4i r;
    asm volatile("global_load_dwordx4 %0, %1, off sc0 sc1\n\t"
                 "s_waitcnt vmcnt(0)"
                 : "=v"(r) : "v"(p) : "memory");
    return r;
}

__device__ __forceinline__ void uncached_store16(void* p, v4i v)
{
    asm volatile("global_store_dwordx4 %0, %1, off sc0 sc1"
                 :: "v"(p), "v"(v) : "memory");
}

__global__ __launch_bounds__(SCAN_TPB, 4) void rnn_scan(const float* __restrict__ Wh,
                                                        float* __restrict__ H,
                                                        unsigned long long* __restrict__ hcomm)
{
    __shared__ __align__(16) float hlds[2][HID];   // 16 KB staging (parity)
    __shared__ float pad[18432];                   // +72 KB -> 88 KB: 1 block/CU

    const int tid = threadIdx.x;
    const int bid = blockIdx.x;
    const int wave = tid >> 6;               // 0..15
    const int lane = tid & 63;
    const int c0 = bid * CPB + wave * CPW;   // this wave's first column

    // Keep `pad` allocated: guard the compiler can't fold (runtime ptr bit),
    // volatile store it can't DCE. Harmless either way at runtime.
    if ((((size_t)hcomm) >> 22) & 1) ((volatile float*)pad)[tid] = 0.f;

    // Per-lane weights: rows 4*lane + 256*k + j (k=0..7, j=0..3), cols c0,c0+1
    float4 w0[8], w1[8];
#pragma unroll
    for (int k = 0; k < 8; ++k) {
        const int r = 4 * lane + 256 * k;
        const float* p = Wh + (size_t)r * HID + c0;
        w0[k].x = p[0];                     w1[k].x = p[1];
        w0[k].y = p[(size_t)HID];           w1[k].y = p[(size_t)HID + 1];
        w0[k].z = p[(size_t)(2 * HID)];     w1[k].z = p[(size_t)(2 * HID) + 1];
        w0[k].w = p[(size_t)(3 * HID)];     w1[k].w = p[(size_t)(3 * HID) + 1];
    }

    for (int t = 0; t < T_STEPS - 1; ++t) {
        // xp prefetch (row t+1, own 2 cols). Plain cached load is safe: this
        // location is only overwritten by THIS thread, later this step.
        float2 xp = make_float2(0.f, 0.f);
        if (lane == 0) xp = *(const float2*)&H[(size_t)(t + 1) * HID + c0];

        // Poll own 2 entries of h_t (parity slot t&1): ONE 16B uncached load.
        const char* slot = (const char*)hcomm +
                           (((size_t)(t & 1) * HID + 2 * (size_t)tid) << 3);
        v4i e;
        do {
            e = uncached_load16(slot);
        } while (e.y != t || e.w != t);

        *(float2*)&hlds[t & 1][2 * tid] =
            make_float2(__int_as_float(e.x), __int_as_float(e.z));
        __syncthreads();  // h_t staged; also the skew/overwrite certificate

        // dot(h_t, Wh[:, c0]) and dot(h_t, Wh[:, c0+1])
        const float* hb = hlds[t & 1];
        float s0 = 0.f, s1 = 0.f;
#pragma unroll
        for (int k = 0; k < 8; ++k) {
            float4 hh = *(const float4*)&hb[4 * lane + 256 * k];
            s0 += hh.x * w0[k].x + hh.y * w0[k].y + hh.z * w0[k].z + hh.w * w0[k].w;
            s1 += hh.x * w1[k].x + hh.y * w1[k].y + hh.z * w1[k].z + hh.w * w1[k].w;
        }
#pragma unroll
        for (int m = 1; m < 64; m <<= 1) {
            s0 += __shfl_xor(s0, m, 64);
            s1 += __shfl_xor(s1, m, 64);
        }

        if (lane == 0) {
            float h0 = tanhf(xp.x + s0);
            float h1 = tanhf(xp.y + s1);
            // publish FIRST (critical path): both entries in ONE 16B store
            v4i pub;
            pub.x = __float_as_int(h0); pub.y = t + 1;
            pub.z = __float_as_int(h1); pub.w = t + 1;
            uncached_store16((char*)hcomm +
                             (((size_t)((t + 1) & 1) * HID + (size_t)c0) << 3), pub);
            // output write (only ever read by this thread during the scan)
            *(float2*)&H[(size_t)(t + 1) * HID + c0] = make_float2(h0, h1);
        }
        // no trailing barrier: parity double-buffer + poll certificate
    }
}

// ---------------------------------------------------------------------------
extern "C" void kernel_launch(void* const* d_in, const int* in_sizes, int n_in,
                              void* d_out, int out_size, void* d_ws, size_t ws_size,
                              hipStream_t stream)
{
    const float* X  = (const float*)d_in[0];
    const float* Wx = (const float*)d_in[1];
    const float* Wh = (const float*)d_in[2];
    const float* b  = (const float*)d_in[3];
    float* H = (float*)d_out;
    unsigned long long* hcomm = (unsigned long long*)d_ws;

    // H row 0 = h0 = zeros. hcomm = {0.0f, step=0} == h_0 entries (memset 0
    // gives exactly that), re-done every call for graph-replay determinism.
    hipMemsetAsync(H, 0, HID * sizeof(float), stream);
    hipMemsetAsync(hcomm, 0, 2 * HID * sizeof(unsigned long long), stream);

    dim3 ggrid(HID / BN, T_STEPS / BM);  // (32, 512)
    xproj_gemm<<<ggrid, 256, 0, stream>>>(X, Wx, b, H);

    const float* whp = Wh;
    float* hp = H;
    unsigned long long* cp = hcomm;
    void* args[] = { (void*)&whp, (void*)&hp, (void*)&cp };
    hipLaunchCooperativeKernel((const void*)rnn_scan, dim3(NBLK), dim3(SCAN_TPB),
                               args, 0, stream);
}